// Round 1
// baseline (845.303 us; speedup 1.0000x reference)
//
#include <hip/hip_runtime.h>
#include <hip/hip_bf16.h>

#define A_NUM 15
#define HDIM 128
#define WDIM 128
#define HW (HDIM*WDIM)
#define PER_IMG (A_NUM*HW)      // 245760
#define NIMG 2
#define PRE_N 6000
#define POST_N 1000
#define NBLK 94                 // ceil(6000/64)
#define NPAD (NBLK*64)          // 6016
#define SORTN 8192

// ws layout (bytes)
#define HIST_OFF   0u           // 2*65536*u32 = 524288
#define META_OFF   524288u      // [0..1]=selcnt, [2..3]=T, [4..5]=keepcnt
#define SEL_OFF    524544u      // 2*8192*u64 = 131072
#define BOX_OFF    655616u      // 6 arrays * 2 img * 6016 * f32 = 288768
#define VALID_OFF  944384u      // 2*6016*u32 = 48128
#define KEEP_OFF   992512u      // 2*1024*u32 = 8192
#define MASK_OFF   1000704u     // 2*6016*94*u64 = 9048064  (end ~10.05 MB)

__device__ __forceinline__ unsigned int f2ord(float f) {
    unsigned int u = __float_as_uint(f);
    return (u & 0x80000000u) ? ~u : (u | 0x80000000u);
}
__device__ __forceinline__ float ord2f(unsigned int u) {
    unsigned int s = (u & 0x80000000u) ? (u ^ 0x80000000u) : ~u;
    return __uint_as_float(s);
}

// ---------------- histogram of top-16 ordered score bits -----------------
__global__ void k_hist(const float* __restrict__ cls, unsigned int* __restrict__ hist) {
    int total = NIMG * PER_IMG;
    for (int e = blockIdx.x * blockDim.x + threadIdx.x; e < total; e += gridDim.x * blockDim.x) {
        int img = e / PER_IMG;
        int rem = e - img * PER_IMG;        // linear in (a, h, w) -> coalesced
        float sc = cls[e];
        unsigned int u = f2ord(sc);
        atomicAdd(&hist[img * 65536 + (u >> 16)], 1u);
        (void)rem;
    }
}

// ---------------- find threshold bin T (suffix count >= 6000) ------------
__global__ void k_scan(const unsigned int* __restrict__ hist, unsigned int* __restrict__ meta) {
    __shared__ unsigned int part[256];
    int img = blockIdx.x;
    const unsigned int* h = hist + img * 65536;
    unsigned int s = 0;
    int c = threadIdx.x;
    for (int b = c * 256; b < c * 256 + 256; ++b) s += h[b];
    part[c] = s;
    __syncthreads();
    if (threadIdx.x == 0) {
        unsigned int cum = 0;
        int cstar = 0;
        for (int cc = 255; cc >= 0; --cc) {
            if (cum + part[cc] >= PRE_N) { cstar = cc; break; }
            cum += part[cc];
        }
        int T = cstar * 256;
        for (int b = cstar * 256 + 255; b >= cstar * 256; --b) {
            cum += h[b];
            if (cum >= PRE_N) { T = b; break; }
        }
        meta[2 + img] = (unsigned int)T;
    }
}

// ---------------- gather candidates with bin >= T ------------------------
__global__ void k_gather(const float* __restrict__ cls, unsigned int* __restrict__ meta,
                         unsigned long long* __restrict__ selkeys) {
    int total = NIMG * PER_IMG;
    for (int e = blockIdx.x * blockDim.x + threadIdx.x; e < total; e += gridDim.x * blockDim.x) {
        int img = e / PER_IMG;
        int rem = e - img * PER_IMG;        // rem = a*HW + pos
        int a = rem / HW;
        int pos = rem - a * HW;             // h*WDIM + w
        int m = pos * A_NUM + a;            // index in (h,w,a) flattened order
        float sc = cls[e];
        unsigned int u = f2ord(sc);
        unsigned int T = meta[2 + img];
        if ((u >> 16) >= T) {
            unsigned int p = atomicAdd(&meta[img], 1u);
            if (p < SORTN)
                selkeys[(size_t)img * SORTN + p] =
                    ((unsigned long long)(~u) << 32) | (unsigned int)m;
        }
    }
}

// ---------------- bitonic sort 8192 u64 keys in LDS ----------------------
__global__ __launch_bounds__(1024) void k_sort(unsigned long long* __restrict__ selkeys,
                                               const unsigned int* __restrict__ meta) {
    __shared__ unsigned long long key[SORTN];
    int img = blockIdx.x;
    unsigned int cnt = meta[img];
    if (cnt > SORTN) cnt = SORTN;
    unsigned long long* g = selkeys + (size_t)img * SORTN;
    for (int i = threadIdx.x; i < SORTN; i += blockDim.x)
        key[i] = (i < (int)cnt) ? g[i] : 0xFFFFFFFFFFFFFFFFULL;
    __syncthreads();
    for (int k = 2; k <= SORTN; k <<= 1) {
        for (int j = k >> 1; j > 0; j >>= 1) {
            for (int p = threadIdx.x; p < SORTN / 2; p += blockDim.x) {
                int i = ((p & ~(j - 1)) << 1) | (p & (j - 1));
                int x = i | j;
                bool up = ((i & k) == 0);
                unsigned long long a = key[i], b = key[x];
                if ((a > b) == up) { key[i] = b; key[x] = a; }
            }
            __syncthreads();
        }
    }
    for (int i = threadIdx.x; i < PRE_N; i += blockDim.x) g[i] = key[i];
}

// ---------------- decode boxes for the sorted top-6000 -------------------
__global__ void k_decode(const unsigned long long* __restrict__ selkeys,
                         const float* __restrict__ bbox, const float* __restrict__ anchors,
                         const float* __restrict__ iminfo,
                         float* __restrict__ boxsoa, unsigned int* __restrict__ validArr) {
    int r = blockIdx.x * blockDim.x + threadIdx.x;
    int img = blockIdx.y;
    if (r >= PRE_N) return;
    unsigned long long keyv = selkeys[(size_t)img * SORTN + r];
    unsigned int m = (unsigned int)(keyv & 0xFFFFFFFFu);
    unsigned int u = ~(unsigned int)(keyv >> 32);
    float score = ord2f(u);
    int q = m / A_NUM;
    int a = m - q * A_NUM;
    int w = q & (WDIM - 1);
    int h = q >> 7;
    // NOTE: reference's meshgrid quirk -> x-shift from h, y-shift from w
    float sx = (float)h * 8.0f;
    float sy = (float)w * 8.0f;
    float a0 = __fadd_rn(anchors[a * 4 + 0], sx);
    float a1 = __fadd_rn(anchors[a * 4 + 1], sy);
    float a2 = __fadd_rn(anchors[a * 4 + 2], sx);
    float a3 = __fadd_rn(anchors[a * 4 + 3], sy);
    float ws = __fadd_rn(__fsub_rn(a2, a0), 1.0f);
    float hs = __fadd_rn(__fsub_rn(a3, a1), 1.0f);
    float cx = __fadd_rn(a0, __fmul_rn(0.5f, ws));
    float cy = __fadd_rn(a1, __fmul_rn(0.5f, hs));
    const float* bb = bbox + (size_t)img * 4 * A_NUM * HW;
    int base = h * WDIM + w;
    float dx = bb[(a * 4 + 0) * HW + base];
    float dy = bb[(a * 4 + 1) * HW + base];
    float dwv = bb[(a * 4 + 2) * HW + base];
    float dhv = bb[(a * 4 + 3) * HW + base];
    const float CLIPV = 4.135166556742356f;  // np.float32(log(1000/16))
    float dw = fminf(dwv, CLIPV);
    float dh = fminf(dhv, CLIPV);
    float pcx = __fadd_rn(__fmul_rn(dx, ws), cx);
    float pcy = __fadd_rn(__fmul_rn(dy, hs), cy);
    float pw = __fmul_rn(expf(dw), ws);
    float ph = __fmul_rn(expf(dh), hs);
    float x1 = __fsub_rn(pcx, __fmul_rn(0.5f, pw));
    float y1 = __fsub_rn(pcy, __fmul_rn(0.5f, ph));
    float x2 = __fsub_rn(__fadd_rn(pcx, __fmul_rn(0.5f, pw)), 1.0f);
    float y2 = __fsub_rn(__fadd_rn(pcy, __fmul_rn(0.5f, ph)), 1.0f);
    float him = iminfo[img * 3 + 0], wim = iminfo[img * 3 + 1], scale = iminfo[img * 3 + 2];
    float wmax = __fsub_rn(wim, 1.0f), hmax = __fsub_rn(him, 1.0f);
    x1 = fminf(fmaxf(x1, 0.0f), wmax);
    y1 = fminf(fmaxf(y1, 0.0f), hmax);
    x2 = fminf(fmaxf(x2, 0.0f), wmax);
    y2 = fminf(fmaxf(y2, 0.0f), hmax);
    float bws = __fadd_rn(__fsub_rn(x2, x1), 1.0f);
    float bhs = __fadd_rn(__fsub_rn(y2, y1), 1.0f);
    float minsz = __fmul_rn(0.0f, scale);  // MIN_SIZE * scale
    bool valid = (bws >= minsz) && (bhs >= minsz) &&
                 (__fadd_rn(x1, __fdiv_rn(bws, 2.0f)) < wim) &&
                 (__fadd_rn(y1, __fdiv_rn(bhs, 2.0f)) < him);
    float area = __fmul_rn(bws, bhs);
    boxsoa[(0 * NIMG + img) * NPAD + r] = x1;
    boxsoa[(1 * NIMG + img) * NPAD + r] = y1;
    boxsoa[(2 * NIMG + img) * NPAD + r] = x2;
    boxsoa[(3 * NIMG + img) * NPAD + r] = y2;
    boxsoa[(4 * NIMG + img) * NPAD + r] = area;
    boxsoa[(5 * NIMG + img) * NPAD + r] = score;
    validArr[img * NPAD + r] = valid ? 1u : 0u;
}

// ---------------- NMS suppression bitmask (j > i, iou > 0.7) -------------
__global__ __launch_bounds__(64) void k_mask(const float* __restrict__ boxsoa,
                                             unsigned long long* __restrict__ mask) {
    int jb = blockIdx.x, ib = blockIdx.y, img = blockIdx.z;
    if (jb < ib) return;
    int t = threadIdx.x;
    __shared__ float jx1[64], jy1[64], jx2[64], jy2[64], jar[64];
    const float* X1 = boxsoa + (0 * NIMG + img) * NPAD;
    const float* Y1 = boxsoa + (1 * NIMG + img) * NPAD;
    const float* X2 = boxsoa + (2 * NIMG + img) * NPAD;
    const float* Y2 = boxsoa + (3 * NIMG + img) * NPAD;
    const float* AR = boxsoa + (4 * NIMG + img) * NPAD;
    int j0 = jb * 64;
    int jidx = j0 + t;
    bool jin = jidx < PRE_N;
    jx1[t] = jin ? X1[jidx] : 0.0f;
    jy1[t] = jin ? Y1[jidx] : 0.0f;
    jx2[t] = jin ? X2[jidx] : 0.0f;
    jy2[t] = jin ? Y2[jidx] : 0.0f;
    jar[t] = jin ? AR[jidx] : 1.0f;
    __syncthreads();
    int i = ib * 64 + t;
    unsigned long long bits = 0ULL;
    if (i < PRE_N) {
        float x1 = X1[i], y1 = Y1[i], x2 = X2[i], y2 = Y2[i], ai = AR[i];
        for (int jj = 0; jj < 64; ++jj) {
            int j = j0 + jj;
            if (j <= i || j >= PRE_N) continue;
            float ix1 = fmaxf(x1, jx1[jj]);
            float iy1 = fmaxf(y1, jy1[jj]);
            float ix2 = fminf(x2, jx2[jj]);
            float iy2 = fminf(y2, jy2[jj]);
            float iw = fmaxf(__fadd_rn(__fsub_rn(ix2, ix1), 1.0f), 0.0f);
            float ih = fmaxf(__fadd_rn(__fsub_rn(iy2, iy1), 1.0f), 0.0f);
            float inter = __fmul_rn(iw, ih);
            float denom = __fsub_rn(__fadd_rn(ai, jar[jj]), inter);
            float iou = __fdiv_rn(inter, denom);
            if (iou > 0.7f) bits |= (1ULL << jj);
        }
    }
    mask[((size_t)img * NPAD + (size_t)i) * NBLK + jb] = bits;
}

// ---------------- serial greedy reduce (one block per image) -------------
__global__ __launch_bounds__(128) void k_reduce(const unsigned long long* __restrict__ mask,
                                                const unsigned int* __restrict__ validArr,
                                                unsigned int* __restrict__ meta,
                                                unsigned int* __restrict__ keeplist) {
    int img = blockIdx.x;
    __shared__ unsigned long long remv[NBLK];
    __shared__ unsigned long long diag[64];
    __shared__ unsigned long long s_vw;
    __shared__ unsigned long long s_kb;
    __shared__ int s_cnt;
    __shared__ unsigned short list[1024];
    const unsigned long long* M = mask + (size_t)img * NPAD * NBLK;
    const unsigned int* V = validArr + img * NPAD;
    int t = threadIdx.x;
    if (t < NBLK) remv[t] = 0ULL;
    if (t == 0) s_cnt = 0;
    __syncthreads();
    for (int ib = 0; ib < NBLK; ++ib) {
        if (t < 64) {
            int i = ib * 64 + t;
            diag[t] = M[(size_t)i * NBLK + ib];
            bool p = (i < PRE_N) && (V[i] != 0u);
            unsigned long long bw = __ballot((int)p);
            if (t == 0) s_vw = bw;
        }
        __syncthreads();
        if (t == 0) {
            unsigned long long live = (~remv[ib]) & s_vw;
            unsigned long long kb = 0ULL;
            int cnt = s_cnt;
            while (live) {
                int b = __ffsll(live) - 1;
                kb |= 1ULL << b;
                list[cnt++] = (unsigned short)(ib * 64 + b);
                live &= ~(1ULL << b);
                live &= ~diag[b];
                if (cnt >= POST_N) break;
            }
            s_kb = kb;
            s_cnt = cnt;
        }
        __syncthreads();
        unsigned long long kb = s_kb;
        for (int jb = ib + 1 + t; jb < NBLK; jb += blockDim.x) {
            unsigned long long acc = remv[jb];
            unsigned long long w = kb;
            while (w) {
                int b = __ffsll(w) - 1;
                w &= w - 1;
                acc |= M[(size_t)(ib * 64 + b) * NBLK + jb];
            }
            remv[jb] = acc;
        }
        __syncthreads();
        if (s_cnt >= POST_N) break;
    }
    __syncthreads();
    int cnt = s_cnt;
    if (t == 0) meta[4 + img] = (unsigned int)cnt;
    for (int k = t; k < cnt; k += blockDim.x) keeplist[img * 1024 + k] = (unsigned int)list[k];
}

// ---------------- emit rois + probs --------------------------------------
__global__ void k_out(const float* __restrict__ boxsoa, const unsigned int* __restrict__ meta,
                      const unsigned int* __restrict__ keeplist, float* __restrict__ out) {
    int k = blockIdx.x * blockDim.x + threadIdx.x;
    int img = blockIdx.y;
    if (k >= POST_N) return;
    unsigned int cnt = meta[4 + img];
    float x1 = 0.0f, y1 = 0.0f, x2 = 0.0f, y2 = 0.0f, sc = -1.0f;
    if (k < (int)cnt) {
        int r = (int)keeplist[img * 1024 + k];
        x1 = boxsoa[(0 * NIMG + img) * NPAD + r];
        y1 = boxsoa[(1 * NIMG + img) * NPAD + r];
        x2 = boxsoa[(2 * NIMG + img) * NPAD + r];
        y2 = boxsoa[(3 * NIMG + img) * NPAD + r];
        sc = boxsoa[(5 * NIMG + img) * NPAD + r];
    }
    float* roi = out + (size_t)(img * POST_N + k) * 5;
    roi[0] = (float)img;
    roi[1] = x1;
    roi[2] = y1;
    roi[3] = x2;
    roi[4] = y2;
    out[NIMG * POST_N * 5 + img * POST_N + k] = sc;
}

extern "C" void kernel_launch(void* const* d_in, const int* in_sizes, int n_in,
                              void* d_out, int out_size, void* d_ws, size_t ws_size,
                              hipStream_t stream) {
    const float* cls = (const float*)d_in[0];
    const float* bbox = (const float*)d_in[1];
    const float* iminfo = (const float*)d_in[2];
    const float* anchors = (const float*)d_in[3];
    float* out = (float*)d_out;
    char* ws = (char*)d_ws;

    unsigned int* hist = (unsigned int*)(ws + HIST_OFF);
    unsigned int* meta = (unsigned int*)(ws + META_OFF);
    unsigned long long* selkeys = (unsigned long long*)(ws + SEL_OFF);
    float* boxsoa = (float*)(ws + BOX_OFF);
    unsigned int* validArr = (unsigned int*)(ws + VALID_OFF);
    unsigned int* keeplist = (unsigned int*)(ws + KEEP_OFF);
    unsigned long long* mask = (unsigned long long*)(ws + MASK_OFF);

    hipMemsetAsync(ws, 0, SEL_OFF, stream);  // hist + meta
    k_hist<<<960, 256, 0, stream>>>(cls, hist);
    k_scan<<<2, 256, 0, stream>>>(hist, meta);
    k_gather<<<960, 256, 0, stream>>>(cls, meta, selkeys);
    k_sort<<<2, 1024, 0, stream>>>(selkeys, meta);
    k_decode<<<dim3((PRE_N + 255) / 256, NIMG), 256, 0, stream>>>(selkeys, bbox, anchors, iminfo,
                                                                  boxsoa, validArr);
    k_mask<<<dim3(NBLK, NBLK, NIMG), 64, 0, stream>>>(boxsoa, mask);
    k_reduce<<<2, 128, 0, stream>>>(mask, validArr, meta, keeplist);
    k_out<<<dim3((POST_N + 255) / 256, NIMG), 256, 0, stream>>>(boxsoa, meta, keeplist, out);
}

// Round 2
// 576.304 us; speedup vs baseline: 1.4668x; 1.4668x over previous
//
#include <hip/hip_runtime.h>
#include <hip/hip_bf16.h>

#define A_NUM 15
#define HDIM 128
#define WDIM 128
#define HW (HDIM*WDIM)
#define PER_IMG (A_NUM*HW)      // 245760
#define NIMG 2
#define PRE_N 6000
#define POST_N 1000
#define NBLK 94                 // ceil(6000/64)
#define NPAD (NBLK*64)          // 6016
#define SORTN 8192

// ws layout (bytes)
#define HIST_OFF   0u           // 2*65536*u32 = 524288
#define META_OFF   524288u      // [0..1]=selcnt, [2..3]=T, [4..5]=keepcnt
#define SEL_OFF    524544u      // 2*8192*u64 = 131072
#define BOX_OFF    655616u      // 6 arrays * 2 img * 6016 * f32 = 288768
#define VALID_OFF  944384u      // 2*6016*u32 = 48128
#define KEEP_OFF   992512u      // 2*1024*u32 = 8192
#define MASK_OFF   1000704u     // 2*94*6016*u64 = 9048064  (end ~10.05 MB)

__device__ __forceinline__ unsigned int f2ord(float f) {
    unsigned int u = __float_as_uint(f);
    return (u & 0x80000000u) ? ~u : (u | 0x80000000u);
}
__device__ __forceinline__ float ord2f(unsigned int u) {
    unsigned int s = (u & 0x80000000u) ? (u ^ 0x80000000u) : ~u;
    return __uint_as_float(s);
}

// ---------------- histogram of top-16 ordered score bits -----------------
__global__ void k_hist(const float* __restrict__ cls, unsigned int* __restrict__ hist) {
    int total = NIMG * PER_IMG;
    for (int e = blockIdx.x * blockDim.x + threadIdx.x; e < total; e += gridDim.x * blockDim.x) {
        int img = e / PER_IMG;
        float sc = cls[e];
        unsigned int u = f2ord(sc);
        atomicAdd(&hist[img * 65536 + (u >> 16)], 1u);
    }
}

// ---------------- find threshold bin T (suffix count >= 6000) ------------
__global__ void k_scan(const unsigned int* __restrict__ hist, unsigned int* __restrict__ meta) {
    __shared__ unsigned int part[256];
    int img = blockIdx.x;
    const unsigned int* h = hist + img * 65536;
    unsigned int s = 0;
    int c = threadIdx.x;
    for (int b = c * 256; b < c * 256 + 256; ++b) s += h[b];
    part[c] = s;
    __syncthreads();
    if (threadIdx.x == 0) {
        unsigned int cum = 0;
        int cstar = 0;
        for (int cc = 255; cc >= 0; --cc) {
            if (cum + part[cc] >= PRE_N) { cstar = cc; break; }
            cum += part[cc];
        }
        int T = cstar * 256;
        for (int b = cstar * 256 + 255; b >= cstar * 256; --b) {
            cum += h[b];
            if (cum >= PRE_N) { T = b; break; }
        }
        meta[2 + img] = (unsigned int)T;
    }
}

// ---------------- gather candidates with bin >= T ------------------------
__global__ void k_gather(const float* __restrict__ cls, unsigned int* __restrict__ meta,
                         unsigned long long* __restrict__ selkeys) {
    int total = NIMG * PER_IMG;
    for (int e = blockIdx.x * blockDim.x + threadIdx.x; e < total; e += gridDim.x * blockDim.x) {
        int img = e / PER_IMG;          // uniform per wave: PER_IMG % 64 == 0
        int rem = e - img * PER_IMG;    // rem = a*HW + pos
        int a = rem / HW;
        int pos = rem - a * HW;         // h*WDIM + w
        int m = pos * A_NUM + a;        // index in (h,w,a) flattened order
        float sc = cls[e];
        unsigned int u = f2ord(sc);
        unsigned int T = meta[2 + img];
        bool pred = (u >> 16) >= T;
        unsigned long long mball = __ballot((int)pred);
        if (pred) {
            int lane = (int)(threadIdx.x & 63u);
            int leader = __ffsll(mball) - 1;
            unsigned int base = 0;
            if (lane == leader)
                base = atomicAdd(&meta[img], (unsigned int)__popcll(mball));
            base = (unsigned int)__shfl((int)base, leader);
            unsigned int p = base + (unsigned int)__popcll(mball & ((1ULL << lane) - 1ULL));
            if (p < SORTN)
                selkeys[(size_t)img * SORTN + p] =
                    ((unsigned long long)(~u) << 32) | (unsigned int)m;
        }
    }
}

// ---------------- bitonic sort 8192 u64 keys in LDS ----------------------
__global__ __launch_bounds__(1024) void k_sort(unsigned long long* __restrict__ selkeys,
                                               const unsigned int* __restrict__ meta) {
    __shared__ unsigned long long key[SORTN];
    int img = blockIdx.x;
    unsigned int cnt = meta[img];
    if (cnt > SORTN) cnt = SORTN;
    unsigned long long* g = selkeys + (size_t)img * SORTN;
    for (int i = threadIdx.x; i < SORTN; i += blockDim.x)
        key[i] = (i < (int)cnt) ? g[i] : 0xFFFFFFFFFFFFFFFFULL;
    __syncthreads();
    for (int k = 2; k <= SORTN; k <<= 1) {
        for (int j = k >> 1; j > 0; j >>= 1) {
            for (int p = threadIdx.x; p < SORTN / 2; p += blockDim.x) {
                int i = ((p & ~(j - 1)) << 1) | (p & (j - 1));
                int x = i | j;
                bool up = ((i & k) == 0);
                unsigned long long a = key[i], b = key[x];
                if ((a > b) == up) { key[i] = b; key[x] = a; }
            }
            __syncthreads();
        }
    }
    for (int i = threadIdx.x; i < PRE_N; i += blockDim.x) g[i] = key[i];
}

// ---------------- decode boxes for the sorted top-6000 -------------------
__global__ void k_decode(const unsigned long long* __restrict__ selkeys,
                         const float* __restrict__ bbox, const float* __restrict__ anchors,
                         const float* __restrict__ iminfo,
                         float* __restrict__ boxsoa, unsigned int* __restrict__ validArr) {
    int r = blockIdx.x * blockDim.x + threadIdx.x;
    int img = blockIdx.y;
    if (r >= PRE_N) return;
    unsigned long long keyv = selkeys[(size_t)img * SORTN + r];
    unsigned int m = (unsigned int)(keyv & 0xFFFFFFFFu);
    unsigned int u = ~(unsigned int)(keyv >> 32);
    float score = ord2f(u);
    int q = m / A_NUM;
    int a = m - q * A_NUM;
    int w = q & (WDIM - 1);
    int h = q >> 7;
    // NOTE: reference's meshgrid quirk -> x-shift from h, y-shift from w
    float sx = (float)h * 8.0f;
    float sy = (float)w * 8.0f;
    float a0 = __fadd_rn(anchors[a * 4 + 0], sx);
    float a1 = __fadd_rn(anchors[a * 4 + 1], sy);
    float a2 = __fadd_rn(anchors[a * 4 + 2], sx);
    float a3 = __fadd_rn(anchors[a * 4 + 3], sy);
    float ws = __fadd_rn(__fsub_rn(a2, a0), 1.0f);
    float hs = __fadd_rn(__fsub_rn(a3, a1), 1.0f);
    float cx = __fadd_rn(a0, __fmul_rn(0.5f, ws));
    float cy = __fadd_rn(a1, __fmul_rn(0.5f, hs));
    const float* bb = bbox + (size_t)img * 4 * A_NUM * HW;
    int base = h * WDIM + w;
    float dx = bb[(a * 4 + 0) * HW + base];
    float dy = bb[(a * 4 + 1) * HW + base];
    float dwv = bb[(a * 4 + 2) * HW + base];
    float dhv = bb[(a * 4 + 3) * HW + base];
    const float CLIPV = 4.135166556742356f;  // np.float32(log(1000/16))
    float dw = fminf(dwv, CLIPV);
    float dh = fminf(dhv, CLIPV);
    float pcx = __fadd_rn(__fmul_rn(dx, ws), cx);
    float pcy = __fadd_rn(__fmul_rn(dy, hs), cy);
    float pw = __fmul_rn(expf(dw), ws);
    float ph = __fmul_rn(expf(dh), hs);
    float x1 = __fsub_rn(pcx, __fmul_rn(0.5f, pw));
    float y1 = __fsub_rn(pcy, __fmul_rn(0.5f, ph));
    float x2 = __fsub_rn(__fadd_rn(pcx, __fmul_rn(0.5f, pw)), 1.0f);
    float y2 = __fsub_rn(__fadd_rn(pcy, __fmul_rn(0.5f, ph)), 1.0f);
    float him = iminfo[img * 3 + 0], wim = iminfo[img * 3 + 1], scale = iminfo[img * 3 + 2];
    float wmax = __fsub_rn(wim, 1.0f), hmax = __fsub_rn(him, 1.0f);
    x1 = fminf(fmaxf(x1, 0.0f), wmax);
    y1 = fminf(fmaxf(y1, 0.0f), hmax);
    x2 = fminf(fmaxf(x2, 0.0f), wmax);
    y2 = fminf(fmaxf(y2, 0.0f), hmax);
    float bws = __fadd_rn(__fsub_rn(x2, x1), 1.0f);
    float bhs = __fadd_rn(__fsub_rn(y2, y1), 1.0f);
    float minsz = __fmul_rn(0.0f, scale);  // MIN_SIZE * scale
    bool valid = (bws >= minsz) && (bhs >= minsz) &&
                 (__fadd_rn(x1, __fdiv_rn(bws, 2.0f)) < wim) &&
                 (__fadd_rn(y1, __fdiv_rn(bhs, 2.0f)) < him);
    float area = __fmul_rn(bws, bhs);
    boxsoa[(0 * NIMG + img) * NPAD + r] = x1;
    boxsoa[(1 * NIMG + img) * NPAD + r] = y1;
    boxsoa[(2 * NIMG + img) * NPAD + r] = x2;
    boxsoa[(3 * NIMG + img) * NPAD + r] = y2;
    boxsoa[(4 * NIMG + img) * NPAD + r] = area;
    boxsoa[(5 * NIMG + img) * NPAD + r] = score;
    validArr[img * NPAD + r] = valid ? 1u : 0u;
}

// ------- symmetric suppression matrix, column-major Mc[img][kb][i] -------
// Mc word = bits j (in block kb) with iou(i,j) > 0.7, j != i.  Only tiles
// kb <= ib(i) are computed (the reduce never reads kb > ib).
__global__ __launch_bounds__(64) void k_mask(const float* __restrict__ boxsoa,
                                             unsigned long long* __restrict__ Mc) {
    int kb = blockIdx.x, ib = blockIdx.y, img = blockIdx.z;
    if (kb > ib) return;
    int t = threadIdx.x;
    __shared__ float jx1[64], jy1[64], jx2[64], jy2[64], jar[64];
    const float* X1 = boxsoa + (0 * NIMG + img) * NPAD;
    const float* Y1 = boxsoa + (1 * NIMG + img) * NPAD;
    const float* X2 = boxsoa + (2 * NIMG + img) * NPAD;
    const float* Y2 = boxsoa + (3 * NIMG + img) * NPAD;
    const float* AR = boxsoa + (4 * NIMG + img) * NPAD;
    int j0 = kb * 64;
    int jidx = j0 + t;
    bool jin = jidx < PRE_N;
    jx1[t] = jin ? X1[jidx] : 0.0f;
    jy1[t] = jin ? Y1[jidx] : 0.0f;
    jx2[t] = jin ? X2[jidx] : 0.0f;
    jy2[t] = jin ? Y2[jidx] : 0.0f;
    jar[t] = jin ? AR[jidx] : 1.0f;
    __syncthreads();
    int i = ib * 64 + t;
    unsigned long long bits = 0ULL;
    if (i < PRE_N) {
        float x1 = X1[i], y1 = Y1[i], x2 = X2[i], y2 = Y2[i], ai = AR[i];
        for (int jj = 0; jj < 64; ++jj) {
            int j = j0 + jj;
            if (j == i || j >= PRE_N) continue;
            float ix1 = fmaxf(x1, jx1[jj]);
            float iy1 = fmaxf(y1, jy1[jj]);
            float ix2 = fminf(x2, jx2[jj]);
            float iy2 = fminf(y2, jy2[jj]);
            float iw = fmaxf(__fadd_rn(__fsub_rn(ix2, ix1), 1.0f), 0.0f);
            float ih = fmaxf(__fadd_rn(__fsub_rn(iy2, iy1), 1.0f), 0.0f);
            float inter = __fmul_rn(iw, ih);
            float denom = __fsub_rn(__fadd_rn(ai, jar[jj]), inter);
            float iou = __fdiv_rn(inter, denom);
            if (iou > 0.7f) bits |= (1ULL << jj);
        }
    }
    Mc[((size_t)img * NBLK + kb) * NPAD + i] = bits;
}

// ---------------- greedy reduce: one wave per image ----------------------
// Lane t of block-step ib owns box i = ib*64+t.  Suppression by earlier
// kept boxes = OR over kb<ib of (Mc[kb][i] & kept[kb]) -- coalesced,
// independent loads.  Within-block greedy is a ballot loop (no LDS chain).
__global__ __launch_bounds__(64) void k_reduce(const unsigned long long* __restrict__ Mc,
                                               const unsigned int* __restrict__ validArr,
                                               unsigned int* __restrict__ meta,
                                               unsigned int* __restrict__ keeplist) {
    int img = blockIdx.x;
    int t = threadIdx.x;
    __shared__ unsigned long long kept[NBLK];
    __shared__ unsigned short list[POST_N];
    const unsigned long long* M = Mc + (size_t)img * NBLK * NPAD;
    const unsigned int* V = validArr + img * NPAD;
    int cnt = 0;
    for (int ib = 0; ib < NBLK; ++ib) {
        int i = ib * 64 + t;
        bool alive = (i < PRE_N) && (V[i] != 0u);
        unsigned long long colb = M[(size_t)ib * NPAD + i];
        unsigned long long supw = 0ULL;
        #pragma unroll 8
        for (int kb = 0; kb < ib; ++kb) {
            unsigned long long kw = kept[kb];
            unsigned long long cw = M[(size_t)kb * NPAD + i];
            supw |= (cw & kw);
        }
        if (supw) alive = false;
        unsigned long long keptbits = 0ULL;
        unsigned long long pending = __ballot((int)alive);
        while (pending) {
            int b = __ffsll(pending) - 1;
            keptbits |= 1ULL << b;
            if (t == 0) list[cnt] = (unsigned short)(ib * 64 + b);
            ++cnt;
            if (cnt >= POST_N) break;
            if (t > b && ((colb >> b) & 1ULL)) alive = false;
            pending = __ballot((int)alive) & ~keptbits;
        }
        if (t == 0) kept[ib] = keptbits;
        __syncthreads();
        if (cnt >= POST_N) break;
    }
    __syncthreads();
    if (t == 0) meta[4 + img] = (unsigned int)cnt;
    for (int k2 = t; k2 < cnt; k2 += 64)
        keeplist[img * 1024 + k2] = (unsigned int)list[k2];
}

// ---------------- emit rois + probs --------------------------------------
__global__ void k_out(const float* __restrict__ boxsoa, const unsigned int* __restrict__ meta,
                      const unsigned int* __restrict__ keeplist, float* __restrict__ out) {
    int k = blockIdx.x * blockDim.x + threadIdx.x;
    int img = blockIdx.y;
    if (k >= POST_N) return;
    unsigned int cnt = meta[4 + img];
    float x1 = 0.0f, y1 = 0.0f, x2 = 0.0f, y2 = 0.0f, sc = -1.0f;
    if (k < (int)cnt) {
        int r = (int)keeplist[img * 1024 + k];
        x1 = boxsoa[(0 * NIMG + img) * NPAD + r];
        y1 = boxsoa[(1 * NIMG + img) * NPAD + r];
        x2 = boxsoa[(2 * NIMG + img) * NPAD + r];
        y2 = boxsoa[(3 * NIMG + img) * NPAD + r];
        sc = boxsoa[(5 * NIMG + img) * NPAD + r];
    }
    float* roi = out + (size_t)(img * POST_N + k) * 5;
    roi[0] = (float)img;
    roi[1] = x1;
    roi[2] = y1;
    roi[3] = x2;
    roi[4] = y2;
    out[NIMG * POST_N * 5 + img * POST_N + k] = sc;
}

extern "C" void kernel_launch(void* const* d_in, const int* in_sizes, int n_in,
                              void* d_out, int out_size, void* d_ws, size_t ws_size,
                              hipStream_t stream) {
    const float* cls = (const float*)d_in[0];
    const float* bbox = (const float*)d_in[1];
    const float* iminfo = (const float*)d_in[2];
    const float* anchors = (const float*)d_in[3];
    float* out = (float*)d_out;
    char* ws = (char*)d_ws;

    unsigned int* hist = (unsigned int*)(ws + HIST_OFF);
    unsigned int* meta = (unsigned int*)(ws + META_OFF);
    unsigned long long* selkeys = (unsigned long long*)(ws + SEL_OFF);
    float* boxsoa = (float*)(ws + BOX_OFF);
    unsigned int* validArr = (unsigned int*)(ws + VALID_OFF);
    unsigned int* keeplist = (unsigned int*)(ws + KEEP_OFF);
    unsigned long long* mask = (unsigned long long*)(ws + MASK_OFF);

    hipMemsetAsync(ws, 0, SEL_OFF, stream);  // hist + meta
    k_hist<<<960, 256, 0, stream>>>(cls, hist);
    k_scan<<<2, 256, 0, stream>>>(hist, meta);
    k_gather<<<960, 256, 0, stream>>>(cls, meta, selkeys);
    k_sort<<<2, 1024, 0, stream>>>(selkeys, meta);
    k_decode<<<dim3((PRE_N + 255) / 256, NIMG), 256, 0, stream>>>(selkeys, bbox, anchors, iminfo,
                                                                  boxsoa, validArr);
    k_mask<<<dim3(NBLK, NBLK, NIMG), 64, 0, stream>>>(boxsoa, mask);
    k_reduce<<<NIMG, 64, 0, stream>>>(mask, validArr, meta, keeplist);
    k_out<<<dim3((POST_N + 255) / 256, NIMG), 256, 0, stream>>>(boxsoa, meta, keeplist, out);
}

// Round 3
// 473.801 us; speedup vs baseline: 1.7841x; 1.2163x over previous
//
#include <hip/hip_runtime.h>
#include <hip/hip_bf16.h>

#define A_NUM 15
#define HDIM 128
#define WDIM 128
#define HW (HDIM*WDIM)
#define PER_IMG (A_NUM*HW)      // 245760
#define NIMG 2
#define PRE_N 6000
#define POST_N 1000
#define NBLK 94                 // ceil(6000/64)
#define NPAD (NBLK*64)          // 6016
#define SORTN 8192
#define BLKC 120                // hist blocks per image
#define ITERC 8                 // 256*8 = 2048 elems per hist block

// ws layout (bytes)
#define META_OFF   0u           // [0..1]=selcnt [2..3]=T [4..5]=keepcnt [6..7]=C* [8..9]=cumAbove
#define COARSE_OFF 64u          // 2*120*256*u32 = 245760
#define FINE_OFF   245824u      // 245760
#define SEL_OFF    491584u      // 2*8192*u64 = 131072
#define BOX_OFF    622656u      // 6*2*6016*f32 = 288768
#define VALID_OFF  911424u      // 2*6016*u32 = 48128
#define KEEP_OFF   959552u      // 2*1024*u32 = 8192
#define MASK_OFF   967744u      // 2*94*6016*u64 = 9048064 (end 10,015,808)

__device__ __forceinline__ unsigned int f2ord(float f) {
    unsigned int u = __float_as_uint(f);
    return (u & 0x80000000u) ? ~u : (u | 0x80000000u);
}
__device__ __forceinline__ float ord2f(unsigned int u) {
    unsigned int s = (u & 0x80000000u) ? (u ^ 0x80000000u) : ~u;
    return __uint_as_float(s);
}

// ---------- coarse 256-bin histogram (u>>24), LDS per-wave sub-hists -----
__global__ __launch_bounds__(256) void k_histc(const float* __restrict__ cls,
                                               unsigned int* __restrict__ coarse) {
    __shared__ unsigned int h[4][256];
    int img = blockIdx.y, blk = blockIdx.x;
    int t = threadIdx.x, wv = t >> 6;
    h[0][t] = 0; h[1][t] = 0; h[2][t] = 0; h[3][t] = 0;
    __syncthreads();
    int base = img * PER_IMG + blk * (256 * ITERC);
    #pragma unroll
    for (int it = 0; it < ITERC; ++it) {
        unsigned int u = f2ord(cls[base + it * 256 + t]);
        atomicAdd(&h[wv][u >> 24], 1u);
    }
    __syncthreads();
    coarse[((size_t)img * BLKC + blk) * 256 + t] = h[0][t] + h[1][t] + h[2][t] + h[3][t];
}

// ---------- find coarse bin C* (suffix crosses PRE_N) --------------------
__global__ void k_scanc(const unsigned int* __restrict__ coarse, unsigned int* __restrict__ meta) {
    __shared__ unsigned int tot[256];
    int img = blockIdx.x, b = threadIdx.x;
    const unsigned int* base = coarse + (size_t)img * BLKC * 256;
    unsigned int s = 0;
    for (int k = 0; k < BLKC; ++k) s += base[k * 256 + b];
    tot[b] = s;
    __syncthreads();
    if (b == 0) {
        unsigned int cum = 0; int cstar = 0;
        for (int c = 255; c >= 0; --c) {
            if (cum + tot[c] >= PRE_N) { cstar = c; break; }
            cum += tot[c];
        }
        meta[6 + img] = (unsigned int)cstar;
        meta[8 + img] = cum;
    }
}

// ---------- fine 256-bin histogram within coarse bin C* ------------------
__global__ __launch_bounds__(256) void k_histf(const float* __restrict__ cls,
                                               const unsigned int* __restrict__ meta,
                                               unsigned int* __restrict__ fine) {
    __shared__ unsigned int h[4][256];
    int img = blockIdx.y, blk = blockIdx.x;
    int t = threadIdx.x, wv = t >> 6;
    h[0][t] = 0; h[1][t] = 0; h[2][t] = 0; h[3][t] = 0;
    __syncthreads();
    unsigned int cst = meta[6 + img];
    int base = img * PER_IMG + blk * (256 * ITERC);
    #pragma unroll
    for (int it = 0; it < ITERC; ++it) {
        unsigned int u = f2ord(cls[base + it * 256 + t]);
        if ((u >> 24) == cst) atomicAdd(&h[wv][(u >> 16) & 0xFFu], 1u);
    }
    __syncthreads();
    fine[((size_t)img * BLKC + blk) * 256 + t] = h[0][t] + h[1][t] + h[2][t] + h[3][t];
}

// ---------- final 16-bit threshold T; also reset select counters ---------
__global__ void k_scanf(const unsigned int* __restrict__ fine, unsigned int* __restrict__ meta) {
    __shared__ unsigned int tot[256];
    int img = blockIdx.x, b = threadIdx.x;
    const unsigned int* base = fine + (size_t)img * BLKC * 256;
    unsigned int s = 0;
    for (int k = 0; k < BLKC; ++k) s += base[k * 256 + b];
    tot[b] = s;
    __syncthreads();
    if (b == 0) {
        unsigned int cum = meta[8 + img];
        int fstar = 0;
        for (int f = 255; f >= 0; --f) {
            if (cum + tot[f] >= PRE_N) { fstar = f; break; }
            cum += tot[f];
        }
        meta[2 + img] = (meta[6 + img] << 8) | (unsigned int)fstar;
        meta[img] = 0u;  // reset selcnt for k_gather (every replay)
    }
}

// ---------- gather candidates with 16-bit bin >= T -----------------------
__global__ __launch_bounds__(256) void k_gather(const float* __restrict__ cls,
                                                unsigned int* __restrict__ meta,
                                                unsigned long long* __restrict__ selkeys) {
    int tid = blockIdx.x * blockDim.x + threadIdx.x;   // 0..PER_IMG-1 exactly
    unsigned int T0 = meta[2], T1 = meta[3];
    int a = tid / HW;
    int pos = tid - a * HW;                            // h*WDIM + w
    int m = pos * A_NUM + a;                           // (h,w,a) flattened order
    #pragma unroll
    for (int img = 0; img < NIMG; ++img) {
        unsigned int T = img ? T1 : T0;
        float sc = cls[img * PER_IMG + tid];
        unsigned int u = f2ord(sc);
        bool pred = (u >> 16) >= T;
        unsigned long long mball = __ballot((int)pred);
        if (pred) {
            int lane = (int)(threadIdx.x & 63u);
            int leader = __ffsll(mball) - 1;
            unsigned int basep = 0;
            if (lane == leader)
                basep = atomicAdd(&meta[img], (unsigned int)__popcll(mball));
            basep = (unsigned int)__shfl((int)basep, leader);
            unsigned int p = basep + (unsigned int)__popcll(mball & ((1ULL << lane) - 1ULL));
            if (p < SORTN)
                selkeys[(size_t)img * SORTN + p] =
                    ((unsigned long long)(~u) << 32) | (unsigned int)m;
        }
    }
}

// ---------- bitonic sort 8192 u64 keys in LDS ----------------------------
__global__ __launch_bounds__(1024) void k_sort(unsigned long long* __restrict__ selkeys,
                                               const unsigned int* __restrict__ meta) {
    __shared__ unsigned long long key[SORTN];
    int img = blockIdx.x;
    unsigned int cnt = meta[img];
    if (cnt > SORTN) cnt = SORTN;
    unsigned long long* g = selkeys + (size_t)img * SORTN;
    for (int i = threadIdx.x; i < SORTN; i += blockDim.x)
        key[i] = (i < (int)cnt) ? g[i] : 0xFFFFFFFFFFFFFFFFULL;
    __syncthreads();
    for (int k = 2; k <= SORTN; k <<= 1) {
        for (int j = k >> 1; j > 0; j >>= 1) {
            for (int p = threadIdx.x; p < SORTN / 2; p += blockDim.x) {
                int i = ((p & ~(j - 1)) << 1) | (p & (j - 1));
                int x = i | j;
                bool up = ((i & k) == 0);
                unsigned long long a = key[i], b = key[x];
                if ((a > b) == up) { key[i] = b; key[x] = a; }
            }
            __syncthreads();
        }
    }
    for (int i = threadIdx.x; i < PRE_N; i += blockDim.x) g[i] = key[i];
}

// ---------- decode boxes for the sorted top-6000 -------------------------
__global__ void k_decode(const unsigned long long* __restrict__ selkeys,
                         const float* __restrict__ bbox, const float* __restrict__ anchors,
                         const float* __restrict__ iminfo,
                         float* __restrict__ boxsoa, unsigned int* __restrict__ validArr) {
    int r = blockIdx.x * blockDim.x + threadIdx.x;
    int img = blockIdx.y;
    if (r >= PRE_N) return;
    unsigned long long keyv = selkeys[(size_t)img * SORTN + r];
    unsigned int m = (unsigned int)(keyv & 0xFFFFFFFFu);
    unsigned int u = ~(unsigned int)(keyv >> 32);
    float score = ord2f(u);
    int q = m / A_NUM;
    int a = m - q * A_NUM;
    int w = q & (WDIM - 1);
    int h = q >> 7;
    // reference's meshgrid quirk -> x-shift from h, y-shift from w
    float sx = (float)h * 8.0f;
    float sy = (float)w * 8.0f;
    float a0 = __fadd_rn(anchors[a * 4 + 0], sx);
    float a1 = __fadd_rn(anchors[a * 4 + 1], sy);
    float a2 = __fadd_rn(anchors[a * 4 + 2], sx);
    float a3 = __fadd_rn(anchors[a * 4 + 3], sy);
    float ws = __fadd_rn(__fsub_rn(a2, a0), 1.0f);
    float hs = __fadd_rn(__fsub_rn(a3, a1), 1.0f);
    float cx = __fadd_rn(a0, __fmul_rn(0.5f, ws));
    float cy = __fadd_rn(a1, __fmul_rn(0.5f, hs));
    const float* bb = bbox + (size_t)img * 4 * A_NUM * HW;
    int base = h * WDIM + w;
    float dx = bb[(a * 4 + 0) * HW + base];
    float dy = bb[(a * 4 + 1) * HW + base];
    float dwv = bb[(a * 4 + 2) * HW + base];
    float dhv = bb[(a * 4 + 3) * HW + base];
    const float CLIPV = 4.135166556742356f;  // np.float32(log(1000/16))
    float dw = fminf(dwv, CLIPV);
    float dh = fminf(dhv, CLIPV);
    float pcx = __fadd_rn(__fmul_rn(dx, ws), cx);
    float pcy = __fadd_rn(__fmul_rn(dy, hs), cy);
    float pw = __fmul_rn(expf(dw), ws);
    float ph = __fmul_rn(expf(dh), hs);
    float x1 = __fsub_rn(pcx, __fmul_rn(0.5f, pw));
    float y1 = __fsub_rn(pcy, __fmul_rn(0.5f, ph));
    float x2 = __fsub_rn(__fadd_rn(pcx, __fmul_rn(0.5f, pw)), 1.0f);
    float y2 = __fsub_rn(__fadd_rn(pcy, __fmul_rn(0.5f, ph)), 1.0f);
    float him = iminfo[img * 3 + 0], wim = iminfo[img * 3 + 1], scale = iminfo[img * 3 + 2];
    float wmax = __fsub_rn(wim, 1.0f), hmax = __fsub_rn(him, 1.0f);
    x1 = fminf(fmaxf(x1, 0.0f), wmax);
    y1 = fminf(fmaxf(y1, 0.0f), hmax);
    x2 = fminf(fmaxf(x2, 0.0f), wmax);
    y2 = fminf(fmaxf(y2, 0.0f), hmax);
    float bws = __fadd_rn(__fsub_rn(x2, x1), 1.0f);
    float bhs = __fadd_rn(__fsub_rn(y2, y1), 1.0f);
    float minsz = __fmul_rn(0.0f, scale);  // MIN_SIZE * scale
    bool valid = (bws >= minsz) && (bhs >= minsz) &&
                 (__fadd_rn(x1, __fdiv_rn(bws, 2.0f)) < wim) &&
                 (__fadd_rn(y1, __fdiv_rn(bhs, 2.0f)) < him);
    float area = __fmul_rn(bws, bhs);
    boxsoa[(0 * NIMG + img) * NPAD + r] = x1;
    boxsoa[(1 * NIMG + img) * NPAD + r] = y1;
    boxsoa[(2 * NIMG + img) * NPAD + r] = x2;
    boxsoa[(3 * NIMG + img) * NPAD + r] = y2;
    boxsoa[(4 * NIMG + img) * NPAD + r] = area;
    boxsoa[(5 * NIMG + img) * NPAD + r] = score;
    validArr[img * NPAD + r] = valid ? 1u : 0u;
}

// ---------- FULL symmetric suppression matrix, col-major Mc[img][kb][i] --
// Word Mc[kb][i] = bits j (in block kb) with iou(i,j) > 0.7, j != i.
// 4 ib-tiles per 256-thread block share the LDS j-tile; writes coalesced.
__global__ __launch_bounds__(256) void k_mask(const float* __restrict__ boxsoa,
                                              unsigned long long* __restrict__ Mc) {
    int kb = blockIdx.x, ibq = blockIdx.y, img = blockIdx.z;
    int t = threadIdx.x, wv = t >> 6, lane = t & 63;
    __shared__ float jx1[64], jy1[64], jx2[64], jy2[64], jar[64];
    const float* X1 = boxsoa + (0 * NIMG + img) * NPAD;
    const float* Y1 = boxsoa + (1 * NIMG + img) * NPAD;
    const float* X2 = boxsoa + (2 * NIMG + img) * NPAD;
    const float* Y2 = boxsoa + (3 * NIMG + img) * NPAD;
    const float* AR = boxsoa + (4 * NIMG + img) * NPAD;
    int j0 = kb * 64;
    if (t < 64) {
        int jidx = j0 + t;
        bool jin = jidx < PRE_N;
        jx1[t] = jin ? X1[jidx] : 0.0f;
        jy1[t] = jin ? Y1[jidx] : 0.0f;
        jx2[t] = jin ? X2[jidx] : 0.0f;
        jy2[t] = jin ? Y2[jidx] : 0.0f;
        jar[t] = jin ? AR[jidx] : 1.0f;
    }
    __syncthreads();
    int ib = ibq * 4 + wv;
    if (ib >= NBLK) return;
    int i = ib * 64 + lane;
    unsigned long long bits = 0ULL;
    if (i < PRE_N) {
        float x1 = X1[i], y1 = Y1[i], x2 = X2[i], y2 = Y2[i], ai = AR[i];
        for (int jj = 0; jj < 64; ++jj) {
            int j = j0 + jj;
            if (j == i || j >= PRE_N) continue;
            float ix1 = fmaxf(x1, jx1[jj]);
            float iy1 = fmaxf(y1, jy1[jj]);
            float ix2 = fminf(x2, jx2[jj]);
            float iy2 = fminf(y2, jy2[jj]);
            float iw = fmaxf(__fadd_rn(__fsub_rn(ix2, ix1), 1.0f), 0.0f);
            float ih = fmaxf(__fadd_rn(__fsub_rn(iy2, iy1), 1.0f), 0.0f);
            float inter = __fmul_rn(iw, ih);
            float denom = __fsub_rn(__fadd_rn(ai, jar[jj]), inter);
            float iou = __fdiv_rn(inter, denom);
            if (iou > 0.7f) bits |= (1ULL << jj);
        }
    }
    Mc[((size_t)img * NBLK + kb) * NPAD + i] = bits;
}

// ---------- greedy reduce: one wave per image, incremental remv ----------
// remv[jb] = bits of block jb suppressed by kept boxes so far.  Update for
// kept box k uses symmetry: word = Mc[jb][k].  Diag/valid prefetched.
__global__ __launch_bounds__(64) void k_reduce(const unsigned long long* __restrict__ Mc,
                                               const unsigned int* __restrict__ validArr,
                                               unsigned int* __restrict__ meta,
                                               unsigned int* __restrict__ keeplist) {
    int img = blockIdx.x;
    int t = threadIdx.x;
    __shared__ unsigned long long remv[NBLK];
    __shared__ unsigned short list[POST_N];
    const unsigned long long* M = Mc + (size_t)img * NBLK * NPAD;
    const unsigned int* V = validArr + img * NPAD;
    remv[t] = 0ULL;
    if (t + 64 < NBLK) remv[t + 64] = 0ULL;
    __syncthreads();
    int cnt = 0;
    unsigned long long colb_next = M[t];     // Mc[0][0*64+t]
    unsigned int v_next = V[t];
    for (int ib = 0; ib < NBLK; ++ib) {
        unsigned long long colb = colb_next;
        unsigned int vv = v_next;
        if (ib + 1 < NBLK) {
            colb_next = M[(size_t)(ib + 1) * NPAD + (ib + 1) * 64 + t];
            v_next = V[(ib + 1) * 64 + t];
        }
        int i = ib * 64 + t;
        unsigned long long rw = remv[ib];
        bool alive = (i < PRE_N) && (vv != 0u) && !((rw >> t) & 1ULL);
        unsigned long long keptbits = 0ULL;
        unsigned long long pending = __ballot((int)alive);
        while (pending) {
            int b = __ffsll(pending) - 1;
            keptbits |= 1ULL << b;
            if (t == 0) list[cnt] = (unsigned short)(ib * 64 + b);
            ++cnt;
            if (cnt >= POST_N) break;
            if (t > b && ((colb >> b) & 1ULL)) alive = false;
            pending = __ballot((int)alive) & ~keptbits;
        }
        if (cnt >= POST_N) break;
        if (keptbits) {
            int jb0 = ib + 1 + t;
            int jb1 = jb0 + 64;
            unsigned long long acc0 = 0ULL, acc1 = 0ULL;
            int rbase = ib * 64;
            unsigned long long w = keptbits;
            while (w) {
                int b0 = __ffsll(w) - 1; w &= w - 1;
                int b1 = -1, b2 = -1, b3 = -1;
                if (w) { b1 = __ffsll(w) - 1; w &= w - 1; }
                if (w) { b2 = __ffsll(w) - 1; w &= w - 1; }
                if (w) { b3 = __ffsll(w) - 1; w &= w - 1; }
                if (jb0 < NBLK) {
                    size_t c0 = (size_t)jb0 * NPAD + rbase;
                    unsigned long long u0 = M[c0 + b0];
                    unsigned long long u1 = (b1 >= 0) ? M[c0 + b1] : 0ULL;
                    unsigned long long u2 = (b2 >= 0) ? M[c0 + b2] : 0ULL;
                    unsigned long long u3 = (b3 >= 0) ? M[c0 + b3] : 0ULL;
                    acc0 |= u0 | u1 | u2 | u3;
                }
                if (jb1 < NBLK) {
                    size_t c1 = (size_t)jb1 * NPAD + rbase;
                    unsigned long long u0 = M[c1 + b0];
                    unsigned long long u1 = (b1 >= 0) ? M[c1 + b1] : 0ULL;
                    unsigned long long u2 = (b2 >= 0) ? M[c1 + b2] : 0ULL;
                    unsigned long long u3 = (b3 >= 0) ? M[c1 + b3] : 0ULL;
                    acc1 |= u0 | u1 | u2 | u3;
                }
            }
            if (jb0 < NBLK) remv[jb0] |= acc0;
            if (jb1 < NBLK) remv[jb1] |= acc1;
        }
        __syncthreads();
    }
    __syncthreads();
    if (t == 0) meta[4 + img] = (unsigned int)cnt;
    for (int k2 = t; k2 < cnt; k2 += 64)
        keeplist[img * 1024 + k2] = (unsigned int)list[k2];
}

// ---------- emit rois + probs --------------------------------------------
__global__ void k_out(const float* __restrict__ boxsoa, const unsigned int* __restrict__ meta,
                      const unsigned int* __restrict__ keeplist, float* __restrict__ out) {
    int k = blockIdx.x * blockDim.x + threadIdx.x;
    int img = blockIdx.y;
    if (k >= POST_N) return;
    unsigned int cnt = meta[4 + img];
    float x1 = 0.0f, y1 = 0.0f, x2 = 0.0f, y2 = 0.0f, sc = -1.0f;
    if (k < (int)cnt) {
        int r = (int)keeplist[img * 1024 + k];
        x1 = boxsoa[(0 * NIMG + img) * NPAD + r];
        y1 = boxsoa[(1 * NIMG + img) * NPAD + r];
        x2 = boxsoa[(2 * NIMG + img) * NPAD + r];
        y2 = boxsoa[(3 * NIMG + img) * NPAD + r];
        sc = boxsoa[(5 * NIMG + img) * NPAD + r];
    }
    float* roi = out + (size_t)(img * POST_N + k) * 5;
    roi[0] = (float)img;
    roi[1] = x1;
    roi[2] = y1;
    roi[3] = x2;
    roi[4] = y2;
    out[NIMG * POST_N * 5 + img * POST_N + k] = sc;
}

extern "C" void kernel_launch(void* const* d_in, const int* in_sizes, int n_in,
                              void* d_out, int out_size, void* d_ws, size_t ws_size,
                              hipStream_t stream) {
    const float* cls = (const float*)d_in[0];
    const float* bbox = (const float*)d_in[1];
    const float* iminfo = (const float*)d_in[2];
    const float* anchors = (const float*)d_in[3];
    float* out = (float*)d_out;
    char* ws = (char*)d_ws;

    unsigned int* meta = (unsigned int*)(ws + META_OFF);
    unsigned int* coarse = (unsigned int*)(ws + COARSE_OFF);
    unsigned int* fine = (unsigned int*)(ws + FINE_OFF);
    unsigned long long* selkeys = (unsigned long long*)(ws + SEL_OFF);
    float* boxsoa = (float*)(ws + BOX_OFF);
    unsigned int* validArr = (unsigned int*)(ws + VALID_OFF);
    unsigned int* keeplist = (unsigned int*)(ws + KEEP_OFF);
    unsigned long long* mask = (unsigned long long*)(ws + MASK_OFF);

    k_histc<<<dim3(BLKC, NIMG), 256, 0, stream>>>(cls, coarse);
    k_scanc<<<NIMG, 256, 0, stream>>>(coarse, meta);
    k_histf<<<dim3(BLKC, NIMG), 256, 0, stream>>>(cls, meta, fine);
    k_scanf<<<NIMG, 256, 0, stream>>>(fine, meta);
    k_gather<<<PER_IMG / 256, 256, 0, stream>>>(cls, meta, selkeys);
    k_sort<<<NIMG, 1024, 0, stream>>>(selkeys, meta);
    k_decode<<<dim3((PRE_N + 255) / 256, NIMG), 256, 0, stream>>>(selkeys, bbox, anchors, iminfo,
                                                                  boxsoa, validArr);
    k_mask<<<dim3(NBLK, (NBLK + 3) / 4, NIMG), 256, 0, stream>>>(boxsoa, mask);
    k_reduce<<<NIMG, 64, 0, stream>>>(mask, validArr, meta, keeplist);
    k_out<<<dim3((POST_N + 255) / 256, NIMG), 256, 0, stream>>>(boxsoa, meta, keeplist, out);
}